// Round 1
// baseline (937.922 us; speedup 1.0000x reference)
//
#include <hip/hip_runtime.h>

#define N_NODES 50000
#define N_EDGES 800000
#define IN_CH 128
#define HID_CH 96
#define OUT_CH 40
#define EPS 1e-5f

// ---------------- CSR build ----------------

__global__ void count_kernel(const int* __restrict__ ei, int* __restrict__ cnt) {
    int e = blockIdx.x * blockDim.x + threadIdx.x;
    if (e >= N_EDGES) return;
    int s = ei[e], d = ei[N_EDGES + e];
    if (s != d) atomicAdd(&cnt[d], 1);
}

__global__ void norm_kernel(const int* __restrict__ cnt, float* __restrict__ dinv,
                            float* __restrict__ selfw) {
    int n = blockIdx.x * blockDim.x + threadIdx.x;
    if (n >= N_NODES) return;
    float deg = (float)(cnt[n] + 1);   // +1 self-loop
    dinv[n]  = rsqrtf(deg);
    selfw[n] = 1.0f / deg;
}

// single-block exclusive scan of cnt -> row_start[0..N_NODES]
__global__ void scan_kernel(const int* __restrict__ cnt, int* __restrict__ row_start) {
    __shared__ int partial[256];
    const int T = 256;
    int tid = threadIdx.x;
    int seg = (N_NODES + T - 1) / T;            // 196
    int s0 = tid * seg;
    int s1 = s0 + seg; if (s1 > N_NODES) s1 = N_NODES;
    int sum = 0;
    for (int i = s0; i < s1; i++) sum += cnt[i];
    partial[tid] = sum;
    __syncthreads();
    if (tid == 0) {
        int acc = 0;
        for (int i = 0; i < T; i++) { int v = partial[i]; partial[i] = acc; acc += v; }
    }
    __syncthreads();
    int acc = partial[tid];
    for (int i = s0; i < s1; i++) { row_start[i] = acc; acc += cnt[i]; }
    if (tid == T - 1) row_start[N_NODES] = acc;
}

__global__ void fill_kernel(const int* __restrict__ ei, const int* __restrict__ row_start,
                            int* __restrict__ fillp, const float* __restrict__ dinv,
                            int* __restrict__ col, float* __restrict__ wcsr) {
    int e = blockIdx.x * blockDim.x + threadIdx.x;
    if (e >= N_EDGES) return;
    int s = ei[e], d = ei[N_EDGES + e];
    if (s == d) return;                          // self-edges have weight 0 -> skip
    int p = atomicAdd(&fillp[d], 1);
    int idx = row_start[d] + p;
    col[idx]  = s;
    wcsr[idx] = dinv[s] * dinv[d];
}

// ---------------- GEMM: out[n,o] = blend((1-beta)*X[n,o],  beta * sum_k X[n,k]*W[o,k]) ----
// X: [N, K] row-major, W: [C, K] row-major (i.e. X @ W^T)

template <int K, int C, bool BLEND>
__global__ __launch_bounds__(256) void gemm_kernel(const float* __restrict__ X,
                                                   const float* __restrict__ W,
                                                   float* __restrict__ out, float beta) {
    constexpr int KP = K + 1;
    constexpr int CJ = (C + 15) / 16;
    __shared__ float sW[C * KP];
    __shared__ float sX[16 * KP];
    int tid = threadIdx.x;
    for (int i = tid; i < C * K; i += 256) sW[(i / K) * KP + (i % K)] = W[i];
    int n0 = blockIdx.x * 16;
    for (int i = tid; i < 16 * K; i += 256) {
        int nl = i / K, k = i % K;
        int n = n0 + nl;
        sX[nl * KP + k] = (n < N_NODES) ? X[n * K + k] : 0.0f;
    }
    __syncthreads();
    int nl = tid >> 4;          // 0..15
    int ob = tid & 15;          // 0..15
    int n = n0 + nl;
    if (n >= N_NODES) return;
    float acc[CJ];
#pragma unroll
    for (int j = 0; j < CJ; j++) acc[j] = 0.0f;
    for (int k = 0; k < K; k++) {
        float xv = sX[nl * KP + k];
#pragma unroll
        for (int j = 0; j < CJ; j++) {
            int o = ob + j * 16;
            if ((C & 15) == 0 || o < C) acc[j] += xv * sW[o * KP + k];
        }
    }
#pragma unroll
    for (int j = 0; j < CJ; j++) {
        int o = ob + j * 16;
        if ((C & 15) == 0 || o < C) {
            float v = acc[j];
            if (BLEND) v = (1.0f - beta) * sX[nl * KP + o] + beta * v;
            out[n * C + o] = v;
        }
    }
}

// ---------------- BatchNorm ----------------

__global__ void bn_stats(const float* __restrict__ h, float* __restrict__ sums,
                         float* __restrict__ sumsq) {
    __shared__ float ssum[HID_CH], ssq[HID_CH];
    int tid = threadIdx.x;
    if (tid < HID_CH) { ssum[tid] = 0.0f; ssq[tid] = 0.0f; }
    __syncthreads();
    const int total = N_NODES * HID_CH;
    for (int idx = blockIdx.x * blockDim.x + tid; idx < total; idx += gridDim.x * blockDim.x) {
        float v = h[idx];
        int c = idx % HID_CH;
        atomicAdd(&ssum[c], v);
        atomicAdd(&ssq[c], v * v);
    }
    __syncthreads();
    if (tid < HID_CH) {
        atomicAdd(&sums[tid], ssum[tid]);
        atomicAdd(&sumsq[tid], ssq[tid]);
    }
}

__global__ void bn_finalize(const float* __restrict__ sums, const float* __restrict__ sumsq,
                            float* __restrict__ mu, float* __restrict__ inv) {
    int c = threadIdx.x;
    if (c >= HID_CH) return;
    float m = sums[c] / (float)N_NODES;
    float var = sumsq[c] / (float)N_NODES - m * m;
    mu[c]  = m;
    inv[c] = rsqrtf(var + EPS);
}

template <bool COPY_H0>
__global__ void bn_apply(float* __restrict__ h, float* __restrict__ h0,
                         const float* __restrict__ mu, const float* __restrict__ inv) {
    int idx = blockIdx.x * blockDim.x + threadIdx.x;
    if (idx >= N_NODES * HID_CH) return;
    int c = idx % HID_CH;
    float v = (h[idx] - mu[c]) * inv[c];
    v = fmaxf(v, 0.0f);
    h[idx] = v;
    if (COPY_H0) h0[idx] = v;
}

// ---------------- SpMM (CSR gather) ----------------
// LAYER: out = 0.9*(selfw*t + sum_j w_j * t[col_j]) + 0.1*h0
// else : out =      selfw*t + sum_j w_j * t[col_j]

template <int C, bool LAYER>
__global__ void spmm_kernel(const float* __restrict__ t, const float* __restrict__ h0,
                            const int* __restrict__ row_start, const int* __restrict__ col,
                            const float* __restrict__ wcsr, const float* __restrict__ selfw,
                            float* __restrict__ out) {
    int idx = blockIdx.x * blockDim.x + threadIdx.x;
    if (idx >= N_NODES * C) return;
    int n = idx / C, c = idx % C;
    float acc = selfw[n] * t[idx];
    int rs = row_start[n], re = row_start[n + 1];
    for (int j = rs; j < re; j++) {
        acc += wcsr[j] * t[col[j] * C + c];
    }
    out[idx] = LAYER ? (0.9f * acc + 0.1f * h0[idx]) : acc;
}

// ---------------- launch ----------------

extern "C" void kernel_launch(void* const* d_in, const int* in_sizes, int n_in,
                              void* d_out, int out_size, void* d_ws, size_t ws_size,
                              hipStream_t stream) {
    const float* x  = (const float*)d_in[0];
    const int*   ei = (const int*)d_in[1];
    const float* W0 = (const float*)d_in[2];
    const float* W1 = (const float*)d_in[3];
    const float* W2 = (const float*)d_in[4];
    const float* W3 = (const float*)d_in[5];
    float* out = (float*)d_out;

    char* w = (char*)d_ws;
    auto alloc = [&](size_t bytes) {
        void* p = (void*)w;
        w += (bytes + 255) & ~(size_t)255;
        return p;
    };
    int*   cnt       = (int*)alloc(N_NODES * 4);
    int*   row_start = (int*)alloc((N_NODES + 1) * 4);
    int*   fillp     = (int*)alloc(N_NODES * 4);
    int*   col       = (int*)alloc(N_EDGES * 4);
    float* wcsr      = (float*)alloc(N_EDGES * 4);
    float* dinv      = (float*)alloc(N_NODES * 4);
    float* selfw     = (float*)alloc(N_NODES * 4);
    float* h         = (float*)alloc((size_t)N_NODES * HID_CH * 4);
    float* h0        = (float*)alloc((size_t)N_NODES * HID_CH * 4);
    float* t         = (float*)alloc((size_t)N_NODES * HID_CH * 4);
    float* sums      = (float*)alloc(HID_CH * 4);
    float* sumsq     = (float*)alloc(HID_CH * 4);
    float* mu        = (float*)alloc(HID_CH * 4);
    float* inv       = (float*)alloc(HID_CH * 4);
    float* f40       = t;  // reuse t for final [N,40]

    const int EB = (N_EDGES + 255) / 256;
    const int NB = (N_NODES + 255) / 256;
    const int ELEMB = (N_NODES * HID_CH + 255) / 256;

    hipMemsetAsync(cnt, 0, N_NODES * 4, stream);
    hipMemsetAsync(fillp, 0, N_NODES * 4, stream);
    hipMemsetAsync(sums, 0, HID_CH * 4, stream);
    hipMemsetAsync(sumsq, 0, HID_CH * 4, stream);

    count_kernel<<<EB, 256, 0, stream>>>(ei, cnt);
    norm_kernel<<<NB, 256, 0, stream>>>(cnt, dinv, selfw);
    scan_kernel<<<1, 256, 0, stream>>>(cnt, row_start);
    fill_kernel<<<EB, 256, 0, stream>>>(ei, row_start, fillp, dinv, col, wcsr);

    // layer 0: h = relu(bn(x @ W0^T)); h0 = h
    gemm_kernel<IN_CH, HID_CH, false><<<N_NODES / 16, 256, 0, stream>>>(x, W0, h, 0.0f);
    bn_stats<<<1024, 256, 0, stream>>>(h, sums, sumsq);
    bn_finalize<<<1, HID_CH, 0, stream>>>(sums, sumsq, mu, inv);
    bn_apply<true><<<ELEMB, 256, 0, stream>>>(h, h0, mu, inv);

    // layer 1: beta = 0.5, W1
    gemm_kernel<HID_CH, HID_CH, true><<<N_NODES / 16, 256, 0, stream>>>(h, W1, t, 0.5f);
    spmm_kernel<HID_CH, true><<<ELEMB, 256, 0, stream>>>(t, h0, row_start, col, wcsr, selfw, h);
    hipMemsetAsync(sums, 0, HID_CH * 4, stream);
    hipMemsetAsync(sumsq, 0, HID_CH * 4, stream);
    bn_stats<<<1024, 256, 0, stream>>>(h, sums, sumsq);
    bn_finalize<<<1, HID_CH, 0, stream>>>(sums, sumsq, mu, inv);
    bn_apply<false><<<ELEMB, 256, 0, stream>>>(h, nullptr, mu, inv);

    // layer 2: beta = 0.25, W2
    gemm_kernel<HID_CH, HID_CH, true><<<N_NODES / 16, 256, 0, stream>>>(h, W2, t, 0.25f);
    spmm_kernel<HID_CH, true><<<ELEMB, 256, 0, stream>>>(t, h0, row_start, col, wcsr, selfw, h);
    hipMemsetAsync(sums, 0, HID_CH * 4, stream);
    hipMemsetAsync(sumsq, 0, HID_CH * 4, stream);
    bn_stats<<<1024, 256, 0, stream>>>(h, sums, sumsq);
    bn_finalize<<<1, HID_CH, 0, stream>>>(sums, sumsq, mu, inv);
    bn_apply<false><<<ELEMB, 256, 0, stream>>>(h, nullptr, mu, inv);

    // final: out = spmm(h @ W3^T)
    gemm_kernel<HID_CH, OUT_CH, false><<<N_NODES / 16, 256, 0, stream>>>(h, W3, f40, 0.0f);
    const int OUTB = (N_NODES * OUT_CH + 255) / 256;
    spmm_kernel<OUT_CH, false><<<OUTB, 256, 0, stream>>>(f40, nullptr, row_start, col, wcsr,
                                                         selfw, out);
}

// Round 2
// 630.750 us; speedup vs baseline: 1.4870x; 1.4870x over previous
//
#include <hip/hip_runtime.h>

#define N_NODES 50000
#define N_EDGES 800000
#define IN_CH 128
#define HID_CH 96
#define OUT_CH 40
#define EPS 1e-5f

// ---------------- CSR build ----------------

__global__ void count_kernel(const int* __restrict__ ei, int* __restrict__ cnt) {
    int e = blockIdx.x * blockDim.x + threadIdx.x;
    if (e >= N_EDGES) return;
    int s = ei[e], d = ei[N_EDGES + e];
    if (s != d) atomicAdd(&cnt[d], 1);
}

__global__ void norm_kernel(const int* __restrict__ cnt, float* __restrict__ dinv,
                            float* __restrict__ selfw) {
    int n = blockIdx.x * blockDim.x + threadIdx.x;
    if (n >= N_NODES) return;
    float deg = (float)(cnt[n] + 1);
    dinv[n]  = rsqrtf(deg);
    selfw[n] = 1.0f / deg;
}

__global__ void scan_kernel(const int* __restrict__ cnt, int* __restrict__ row_start) {
    __shared__ int partial[256];
    const int T = 256;
    int tid = threadIdx.x;
    int seg = (N_NODES + T - 1) / T;
    int s0 = tid * seg;
    int s1 = s0 + seg; if (s1 > N_NODES) s1 = N_NODES;
    int sum = 0;
    for (int i = s0; i < s1; i++) sum += cnt[i];
    partial[tid] = sum;
    __syncthreads();
    if (tid == 0) {
        int acc = 0;
        for (int i = 0; i < T; i++) { int v = partial[i]; partial[i] = acc; acc += v; }
    }
    __syncthreads();
    int acc = partial[tid];
    for (int i = s0; i < s1; i++) { row_start[i] = acc; acc += cnt[i]; }
    if (tid == T - 1) row_start[N_NODES] = acc;
}

__global__ void fill_kernel(const int* __restrict__ ei, const int* __restrict__ row_start,
                            int* __restrict__ fillp, const float* __restrict__ dinv,
                            int2* __restrict__ cw) {
    int e = blockIdx.x * blockDim.x + threadIdx.x;
    if (e >= N_EDGES) return;
    int s = ei[e], d = ei[N_EDGES + e];
    if (s == d) return;
    int p = atomicAdd(&fillp[d], 1);
    int idx = row_start[d] + p;
    cw[idx] = make_int2(s, __float_as_int(dinv[s] * dinv[d]));
}

// ---------------- GEMM ----------------
// out[n,o] = beta-blend of X@W^T; X optionally normalized (BN+ReLU) on load;
// optionally accumulates BN stats of the raw output.

template <int K, int C, int NT, bool BLEND, bool NORMX, bool STATS>
__global__ __launch_bounds__(256) void gemm_kernel(
    const float* __restrict__ X, const float* __restrict__ W, float* __restrict__ out,
    const float* __restrict__ insum, const float* __restrict__ insq,
    float* __restrict__ osum, float* __restrict__ osq, float beta) {
    constexpr int KP = K + 4;            // row stride in floats, keeps 16B alignment, bank stride 4
    constexpr int K4 = K / 4;
    constexpr int NR = NT * 16;
    constexpr int CJ = (C + 15) / 16;
    __shared__ float sW[C * KP];
    __shared__ float sX[NR * KP];
    __shared__ float sMu[K], sInv[K];
    __shared__ float ssum[C], ssq[C];
    const int tid = threadIdx.x;
    if (NORMX && tid < K) {
        float m = insum[tid] * (1.0f / N_NODES);
        float var = insq[tid] * (1.0f / N_NODES) - m * m;
        sMu[tid] = m; sInv[tid] = rsqrtf(var + EPS);
    }
    if (STATS && tid < C) { ssum[tid] = 0.0f; ssq[tid] = 0.0f; }
    const float4* W4 = (const float4*)W;
    for (int i = tid; i < C * K4; i += 256) {
        int o = i / K4, k4 = i - o * K4;
        *(float4*)&sW[o * KP + k4 * 4] = W4[i];
    }
    __syncthreads();
    const float4* X4 = (const float4*)X;
    const int ob = tid & 15, nl = tid >> 4;
    const int NTILES = (N_NODES + NR - 1) / NR;
    for (int tile = blockIdx.x; tile < NTILES; tile += gridDim.x) {
        const int n0 = tile * NR;
        for (int i = tid; i < NR * K4; i += 256) {
            int r = i / K4, k4 = i - r * K4;
            int n = n0 + r;
            float4 v = make_float4(0.f, 0.f, 0.f, 0.f);
            if (n < N_NODES) v = X4[n * K4 + k4];
            if (NORMX) {
                int k = k4 * 4;
                v.x = fmaxf((v.x - sMu[k + 0]) * sInv[k + 0], 0.0f);
                v.y = fmaxf((v.y - sMu[k + 1]) * sInv[k + 1], 0.0f);
                v.z = fmaxf((v.z - sMu[k + 2]) * sInv[k + 2], 0.0f);
                v.w = fmaxf((v.w - sMu[k + 3]) * sInv[k + 3], 0.0f);
            }
            *(float4*)&sX[r * KP + k4 * 4] = v;
        }
        __syncthreads();
        float acc[NT][CJ];
#pragma unroll
        for (int t = 0; t < NT; t++)
#pragma unroll
            for (int j = 0; j < CJ; j++) acc[t][j] = 0.0f;
#pragma unroll 4
        for (int k4 = 0; k4 < K4; k4++) {
            float4 xv[NT];
#pragma unroll
            for (int t = 0; t < NT; t++)
                xv[t] = *(const float4*)&sX[(nl + 16 * t) * KP + k4 * 4];
#pragma unroll
            for (int j = 0; j < CJ; j++) {
                int o = ob + j * 16;
                if ((C & 15) == 0 || o < C) {
                    float4 wv = *(const float4*)&sW[o * KP + k4 * 4];
#pragma unroll
                    for (int t = 0; t < NT; t++) {
                        acc[t][j] = fmaf(xv[t].x, wv.x, acc[t][j]);
                        acc[t][j] = fmaf(xv[t].y, wv.y, acc[t][j]);
                        acc[t][j] = fmaf(xv[t].z, wv.z, acc[t][j]);
                        acc[t][j] = fmaf(xv[t].w, wv.w, acc[t][j]);
                    }
                }
            }
        }
#pragma unroll
        for (int t = 0; t < NT; t++) {
            int n = n0 + nl + 16 * t;
            if (n < N_NODES) {
#pragma unroll
                for (int j = 0; j < CJ; j++) {
                    int o = ob + j * 16;
                    if ((C & 15) == 0 || o < C) {
                        float v = acc[t][j];
                        if (BLEND) v = (1.0f - beta) * sX[(nl + 16 * t) * KP + o] + beta * v;
                        out[n * C + o] = v;
                        if (STATS) {
                            atomicAdd(&ssum[o], v);
                            atomicAdd(&ssq[o], v * v);
                        }
                    }
                }
            }
        }
        __syncthreads();
    }
    if (STATS && tid < C) {
        atomicAdd(&osum[tid], ssum[tid]);
        atomicAdd(&osq[tid], ssq[tid]);
    }
}

// ---------------- SpMM (CSR gather, float4) ----------------
// LAYER: out = 0.9*(selfw*t + sum w*t[col]) + 0.1*relu(bn(g0)); else plain spmm.
// STATS: accumulate per-channel sum/sumsq of out.

template <int C, bool LAYER, bool STATS>
__global__ __launch_bounds__(256) void spmm_kernel(
    const float4* __restrict__ t4, const float4* __restrict__ g0,
    const float* __restrict__ sums0, const float* __restrict__ sq0,
    const int* __restrict__ row_start, const int2* __restrict__ cw,
    const float* __restrict__ selfw, float4* __restrict__ out4,
    float* __restrict__ osum, float* __restrict__ osq) {
    constexpr int C4 = C / 4;
    __shared__ float sMu[C], sInv[C];
    __shared__ float ssum[C], ssq[C];
    const int tid = threadIdx.x;
    if (LAYER && tid < C) {
        float m = sums0[tid] * (1.0f / N_NODES);
        float var = sq0[tid] * (1.0f / N_NODES) - m * m;
        sMu[tid] = m; sInv[tid] = rsqrtf(var + EPS);
    }
    if (STATS && tid < C) { ssum[tid] = 0.0f; ssq[tid] = 0.0f; }
    __syncthreads();
    const int total = N_NODES * C4;
    for (int idx = blockIdx.x * 256 + tid; idx < total; idx += gridDim.x * 256) {
        int n = idx / C4;
        int c4 = idx - n * C4;
        float sw = selfw[n];
        float4 acc = t4[idx];
        acc.x *= sw; acc.y *= sw; acc.z *= sw; acc.w *= sw;
        int rs = row_start[n], re = row_start[n + 1];
        int j = rs;
        for (; j + 1 < re; j += 2) {
            int2 e0 = cw[j], e1 = cw[j + 1];
            float4 a0 = t4[e0.x * C4 + c4];
            float4 a1 = t4[e1.x * C4 + c4];
            float w0 = __int_as_float(e0.y), w1 = __int_as_float(e1.y);
            acc.x = fmaf(w0, a0.x, acc.x); acc.y = fmaf(w0, a0.y, acc.y);
            acc.z = fmaf(w0, a0.z, acc.z); acc.w = fmaf(w0, a0.w, acc.w);
            acc.x = fmaf(w1, a1.x, acc.x); acc.y = fmaf(w1, a1.y, acc.y);
            acc.z = fmaf(w1, a1.z, acc.z); acc.w = fmaf(w1, a1.w, acc.w);
        }
        if (j < re) {
            int2 e0 = cw[j];
            float4 a0 = t4[e0.x * C4 + c4];
            float w0 = __int_as_float(e0.y);
            acc.x = fmaf(w0, a0.x, acc.x); acc.y = fmaf(w0, a0.y, acc.y);
            acc.z = fmaf(w0, a0.z, acc.z); acc.w = fmaf(w0, a0.w, acc.w);
        }
        if (LAYER) {
            float4 g = g0[idx];
            int c = c4 * 4;
            float h0x = fmaxf((g.x - sMu[c + 0]) * sInv[c + 0], 0.0f);
            float h0y = fmaxf((g.y - sMu[c + 1]) * sInv[c + 1], 0.0f);
            float h0z = fmaxf((g.z - sMu[c + 2]) * sInv[c + 2], 0.0f);
            float h0w = fmaxf((g.w - sMu[c + 3]) * sInv[c + 3], 0.0f);
            acc.x = 0.9f * acc.x + 0.1f * h0x;
            acc.y = 0.9f * acc.y + 0.1f * h0y;
            acc.z = 0.9f * acc.z + 0.1f * h0z;
            acc.w = 0.9f * acc.w + 0.1f * h0w;
        }
        out4[idx] = acc;
        if (STATS) {
            int c = c4 * 4;
            atomicAdd(&ssum[c + 0], acc.x); atomicAdd(&ssq[c + 0], acc.x * acc.x);
            atomicAdd(&ssum[c + 1], acc.y); atomicAdd(&ssq[c + 1], acc.y * acc.y);
            atomicAdd(&ssum[c + 2], acc.z); atomicAdd(&ssq[c + 2], acc.z * acc.z);
            atomicAdd(&ssum[c + 3], acc.w); atomicAdd(&ssq[c + 3], acc.w * acc.w);
        }
    }
    if (STATS) {
        __syncthreads();
        if (tid < C) {
            atomicAdd(&osum[tid], ssum[tid]);
            atomicAdd(&osq[tid], ssq[tid]);
        }
    }
}

// ---------------- launch ----------------

extern "C" void kernel_launch(void* const* d_in, const int* in_sizes, int n_in,
                              void* d_out, int out_size, void* d_ws, size_t ws_size,
                              hipStream_t stream) {
    const float* x  = (const float*)d_in[0];
    const int*   ei = (const int*)d_in[1];
    const float* W0 = (const float*)d_in[2];
    const float* W1 = (const float*)d_in[3];
    const float* W2 = (const float*)d_in[4];
    const float* W3 = (const float*)d_in[5];
    float* out = (float*)d_out;

    char* w = (char*)d_ws;
    auto alloc = [&](size_t bytes) {
        void* p = (void*)w;
        w += (bytes + 255) & ~(size_t)255;
        return p;
    };
    int*   cnt       = (int*)alloc(N_NODES * 4);
    int*   row_start = (int*)alloc((N_NODES + 1) * 4);
    int*   fillp     = (int*)alloc(N_NODES * 4);
    int2*  cw        = (int2*)alloc((size_t)N_EDGES * 8);
    float* dinv      = (float*)alloc(N_NODES * 4);
    float* selfw     = (float*)alloc(N_NODES * 4);
    float* g0        = (float*)alloc((size_t)N_NODES * HID_CH * 4);
    float* t         = (float*)alloc((size_t)N_NODES * HID_CH * 4);
    float* s         = (float*)alloc((size_t)N_NODES * HID_CH * 4);
    float* stats     = (float*)alloc(6 * HID_CH * 4);
    float* sums0 = stats,               * sq0 = stats + HID_CH;
    float* sums1 = stats + 2 * HID_CH,  * sq1 = stats + 3 * HID_CH;
    float* sums2 = stats + 4 * HID_CH,  * sq2 = stats + 5 * HID_CH;

    const int EB = (N_EDGES + 255) / 256;
    const int NB = (N_NODES + 255) / 256;

    hipMemsetAsync(cnt, 0, N_NODES * 4, stream);
    hipMemsetAsync(fillp, 0, N_NODES * 4, stream);
    hipMemsetAsync(stats, 0, 6 * HID_CH * 4, stream);

    count_kernel<<<EB, 256, 0, stream>>>(ei, cnt);
    norm_kernel<<<NB, 256, 0, stream>>>(cnt, dinv, selfw);
    scan_kernel<<<1, 256, 0, stream>>>(cnt, row_start);
    fill_kernel<<<EB, 256, 0, stream>>>(ei, row_start, fillp, dinv, cw);

    // layer 0: g0 = x @ W0^T (raw) + stats0
    gemm_kernel<IN_CH, HID_CH, 1, false, false, true><<<1024, 256, 0, stream>>>(
        x, W0, g0, nullptr, nullptr, sums0, sq0, 0.0f);

    // layer 1: t = blend(hn0, hn0@W1^T, beta=.5) with hn0 = relu(bn(g0))
    gemm_kernel<HID_CH, HID_CH, 2, true, true, false><<<1024, 256, 0, stream>>>(
        g0, W1, t, sums0, sq0, nullptr, nullptr, 0.5f);
    // s = 0.9*spmm(t) + 0.1*hn0, + stats1
    spmm_kernel<HID_CH, true, true><<<2048, 256, 0, stream>>>(
        (const float4*)t, (const float4*)g0, sums0, sq0, row_start, cw, selfw,
        (float4*)s, sums1, sq1);

    // layer 2: t = blend(hn1, hn1@W2^T, beta=.25) with hn1 = relu(bn(s))
    gemm_kernel<HID_CH, HID_CH, 2, true, true, false><<<1024, 256, 0, stream>>>(
        s, W2, t, sums1, sq1, nullptr, nullptr, 0.25f);
    // s = 0.9*spmm(t) + 0.1*hn0, + stats2
    spmm_kernel<HID_CH, true, true><<<2048, 256, 0, stream>>>(
        (const float4*)t, (const float4*)g0, sums0, sq0, row_start, cw, selfw,
        (float4*)s, sums2, sq2);

    // final: t40 = hn2 @ W3^T with hn2 = relu(bn(s)); out = spmm(t40)
    float* f40 = t;
    gemm_kernel<HID_CH, OUT_CH, 2, false, true, false><<<1024, 256, 0, stream>>>(
        s, W3, f40, sums2, sq2, nullptr, nullptr, 0.0f);
    spmm_kernel<OUT_CH, false, false><<<1954, 256, 0, stream>>>(
        (const float4*)f40, nullptr, nullptr, nullptr, row_start, cw, selfw,
        (float4*)out, nullptr, nullptr);
}